// Round 3
// baseline (387.798 us; speedup 1.0000x reference)
//
#include <hip/hip_runtime.h>
#include <hip/hip_bf16.h>

#define S_LEN 2048
#define NBATCH 2
#define DMODEL 1024
#define NHEAD 16
#define NKV 4
#define HDIM 64

typedef __attribute__((ext_vector_type(4))) float f32x4;
typedef __attribute__((ext_vector_type(8))) short s16x8;

// 0.125 (1/sqrt(dk)) * log2(e): Q pre-scale so softmax runs in exp2 domain
#define QSCALE 0.18033688011112042f

__device__ __forceinline__ unsigned short f32_bf16(float f) {
    unsigned int u = __float_as_uint(f);
    u += 0x7FFFu + ((u >> 16) & 1u);
    return (unsigned short)(u >> 16);
}

// ---------------- f32 -> bf16 convert ----------------
__global__ __launch_bounds__(256) void cvt_bf16_k(const float* __restrict__ in,
                                                  unsigned short* __restrict__ out, int n4) {
    int i = blockIdx.x * 256 + threadIdx.x;
    if (i < n4) {
        const float4 v = reinterpret_cast<const float4*>(in)[i];
        ushort4 r;
        r.x = f32_bf16(v.x); r.y = f32_bf16(v.y);
        r.z = f32_bf16(v.z); r.w = f32_bf16(v.w);
        reinterpret_cast<ushort4*>(out)[i] = r;
    }
}

// ---------------- GEMM: C[M][N] = A[M][K] @ W[K][N], bf16 in, f32 acc ----------------
// EPI 0: f32 row-major out.
// EPI 1: rope + *oscale + bf16 head-layout [B][nheads][S][DK].
// EPI 2: bf16 head-layout (no rope).
// EPI 3: bf16 TRANSPOSED head-layout [B][nheads][DK][S]  (for V)
template<int EPI>
__global__ __launch_bounds__(256) void gemm_k(
    const unsigned short* __restrict__ A,
    const unsigned short* __restrict__ W,
    void* __restrict__ Out, int N, int K, int nheads, float oscale)
{
    __shared__ unsigned short As[64][72];   // [m][k], +8 pad
    __shared__ unsigned short Bs[64][72];   // [n][k] (transposed), +8 pad

    const int tid  = threadIdx.x;
    const int lane = tid & 63;
    const int l15  = lane & 15;
    const int l4   = lane >> 4;
    const int wave = tid >> 6;
    const int wr   = (wave >> 1) * 32;
    const int wc   = (wave & 1) * 32;
    const int bm   = blockIdx.y * 64;
    const int bn   = blockIdx.x * 64;

    f32x4 acc[2][2] = {};

    for (int k0 = 0; k0 < K; k0 += 64) {
        #pragma unroll
        for (int cc = 0; cc < 2; ++cc) {
            const int c   = tid + cc * 256;      // 512 chunks of 8 elems
            const int row = c >> 3;
            const int col = (c & 7) * 8;
            *reinterpret_cast<s16x8*>(&As[row][col]) =
                *reinterpret_cast<const s16x8*>(A + (size_t)(bm + row) * K + k0 + col);
            const s16x8 wv =
                *reinterpret_cast<const s16x8*>(W + (size_t)(k0 + row) * N + bn + col);
            #pragma unroll
            for (int i = 0; i < 8; ++i) Bs[col + i][row] = (short)wv[i];
        }
        __syncthreads();
        #pragma unroll
        for (int ks = 0; ks < 2; ++ks) {
            s16x8 af[2], bfv[2];
            #pragma unroll
            for (int i = 0; i < 2; ++i)
                af[i] = *reinterpret_cast<const s16x8*>(&As[wr + i*16 + l15][ks*32 + l4*8]);
            #pragma unroll
            for (int j = 0; j < 2; ++j)
                bfv[j] = *reinterpret_cast<const s16x8*>(&Bs[wc + j*16 + l15][ks*32 + l4*8]);
            #pragma unroll
            for (int i = 0; i < 2; ++i)
                #pragma unroll
                for (int j = 0; j < 2; ++j)
                    acc[i][j] = __builtin_amdgcn_mfma_f32_16x16x32_bf16(
                        af[i], bfv[j], acc[i][j], 0, 0, 0);
        }
        __syncthreads();
    }

    #pragma unroll
    for (int i = 0; i < 2; ++i) {
        #pragma unroll
        for (int j = 0; j < 2; ++j) {
            #pragma unroll
            for (int v = 0; v < 4; ++v) {
                const int gr = bm + wr + i*16 + l4*4 + v;
                const int gc = bn + wc + j*16 + l15;
                float val = acc[i][j][v];
                if (EPI == 0) {
                    reinterpret_cast<float*>(Out)[(size_t)gr * N + gc] = val;
                } else {
                    if (EPI == 1) {
                        const float partner = __shfl_xor(val, 1, 64);
                        const int   jp = (gc & 63) >> 1;      // pair index 0..31
                        const int   hh = gc >> 6;             // head index
                        // inv_freq = 10000^(-2*jp/64)
                        const float inv = __expf((float)jp * (-2.0f / 64.0f) * 9.210340371976184f);
                        const float ang = (float)hh * inv;
                        float sn, cs;
                        __sincosf(ang, &sn, &cs);
                        val = ((gc & 1) == 0) ? (val * cs - partner * sn)
                                              : (partner * sn + val * cs);
                        val *= oscale;
                    }
                    const int b  = gr >> 11;       // / S_LEN
                    const int sr = gr & (S_LEN - 1);
                    const int hh = gc >> 6;
                    const int dk = gc & 63;
                    if (EPI == 3) {
                        reinterpret_cast<unsigned short*>(Out)[
                            (((size_t)b * nheads + hh) * HDIM + dk) * S_LEN + sr] = f32_bf16(val);
                    } else {
                        reinterpret_cast<unsigned short*>(Out)[
                            (((size_t)b * nheads + hh) * S_LEN + sr) * HDIM + dk] = f32_bf16(val);
                    }
                }
            }
        }
    }
}

// ---------------- flash attention (causal, GQA) ----------------
// Q: [B][NHEAD][S][DK] bf16 (rope+QSCALE applied), K: [B][NKV][S][DK],
// Vt: [B][NKV][DK][S] (transposed!), Ctx out: [B][S][NHEAD][DK] bf16
template<bool MASK>
__device__ __forceinline__ void attn_step(
    int kv0, int qb, int l15, int l4,
    const unsigned short* __restrict__ Kp,
    const unsigned short* __restrict__ Vp,
    const s16x8 qf[2], f32x4 o[4], float m[4], float lsum[4],
    unsigned short (*Plds)[72])
{
    // ---- scores: S[16q][64kv] in exp2 domain (Q pre-scaled) ----
    f32x4 s[4] = {};
    #pragma unroll
    for (int c = 0; c < 4; ++c) {
        #pragma unroll
        for (int ks = 0; ks < 2; ++ks) {
            const s16x8 kf = *reinterpret_cast<const s16x8*>(
                Kp + (size_t)(kv0 + c*16 + l15) * HDIM + ks*32 + l4*8);
            s[c] = __builtin_amdgcn_mfma_f32_16x16x32_bf16(qf[ks], kf, s[c], 0, 0, 0);
        }
    }
    // ---- mask (diagonal block only) + online softmax ----
    #pragma unroll
    for (int v = 0; v < 4; ++v) {
        if (MASK) {
            const int qg = qb + l4*4 + v;
            #pragma unroll
            for (int c = 0; c < 4; ++c) {
                const int kvg = kv0 + c*16 + l15;
                s[c][v] = (kvg <= qg) ? s[c][v] : -1e30f;
            }
        }
        float mx = fmaxf(fmaxf(s[0][v], s[1][v]), fmaxf(s[2][v], s[3][v]));
        #pragma unroll
        for (int off = 1; off < 16; off <<= 1)
            mx = fmaxf(mx, __shfl_xor(mx, off, 64));
        const float mnew  = fmaxf(m[v], mx);
        const float scale = exp2f(m[v] - mnew);
        float psum = 0.0f;
        #pragma unroll
        for (int c = 0; c < 4; ++c) {
            const float p = exp2f(s[c][v] - mnew);
            s[c][v] = p;
            psum += p;
        }
        #pragma unroll
        for (int off = 1; off < 16; off <<= 1)
            psum += __shfl_xor(psum, off, 64);
        lsum[v] = lsum[v] * scale + psum;
        m[v] = mnew;
        #pragma unroll
        for (int dkc = 0; dkc < 4; ++dkc) o[dkc][v] *= scale;
    }
    // ---- P (D-layout) -> LDS -> A-frag layout ----
    #pragma unroll
    for (int c = 0; c < 4; ++c)
        #pragma unroll
        for (int v = 0; v < 4; ++v)
            Plds[l4*4 + v][c*16 + l15] = f32_bf16(s[c][v]);
    s16x8 pa[2];
    #pragma unroll
    for (int ks = 0; ks < 2; ++ks)
        pa[ks] = *reinterpret_cast<const s16x8*>(&Plds[l15][ks*32 + l4*8]);
    // ---- PV: O[16q][64dk] += P[16][64] @ V[64][64], V from transposed layout ----
    #pragma unroll
    for (int dkc = 0; dkc < 4; ++dkc) {
        #pragma unroll
        for (int ks = 0; ks < 2; ++ks) {
            const s16x8 vf = *reinterpret_cast<const s16x8*>(
                Vp + (size_t)(dkc*16 + l15) * S_LEN + kv0 + ks*32 + l4*8);
            o[dkc] = __builtin_amdgcn_mfma_f32_16x16x32_bf16(pa[ks], vf, o[dkc], 0, 0, 0);
        }
    }
}

__global__ __launch_bounds__(256) void attn_k(
    const unsigned short* __restrict__ Q,
    const unsigned short* __restrict__ Kb,
    const unsigned short* __restrict__ Vt,
    unsigned short* __restrict__ Ctx)
{
    __shared__ unsigned short Plds[4][16][72];  // per-wave P tile [q16][kv64], pad->72

    const int tid  = threadIdx.x;
    const int lane = tid & 63;
    const int l15  = lane & 15;
    const int l4   = lane >> 4;
    const int wave = tid >> 6;

    // reversed order: biggest causal blocks launch first
    const int qb0 = (gridDim.x - 1 - blockIdx.x) * 64;
    const int h   = blockIdx.y;
    const int b   = blockIdx.z;
    const int g   = h >> 2;   // kv head

    const unsigned short* Qp = Q  + ((size_t)b * NHEAD + h) * S_LEN * HDIM;
    const unsigned short* Kp = Kb + ((size_t)b * NKV  + g) * S_LEN * HDIM;
    const unsigned short* Vp = Vt + ((size_t)b * NKV  + g) * HDIM * S_LEN;

    const int qb = qb0 + wave * 16;   // this wave's 16 q-rows

    s16x8 qf[2];
    #pragma unroll
    for (int ks = 0; ks < 2; ++ks)
        qf[ks] = *reinterpret_cast<const s16x8*>(Qp + (size_t)(qb + l15) * HDIM + ks*32 + l4*8);

    f32x4 o[4] = {};
    float m[4], lsum[4];
    #pragma unroll
    for (int v = 0; v < 4; ++v) { m[v] = -1e30f; lsum[v] = 0.0f; }

    const int kvend = qb + 16;   // causal bound
    // blocks [0, full_end) need no masking; [full_end, kvend) need the compare
    const int full_end = (qb >= 63) ? ((((qb - 63) >> 6) << 6) + 64) : 0;

    int kv0 = 0;
    for (; kv0 < full_end; kv0 += 64)
        attn_step<false>(kv0, qb, l15, l4, Kp, Vp, qf, o, m, lsum, Plds[wave]);
    for (; kv0 < kvend; kv0 += 64)
        attn_step<true >(kv0, qb, l15, l4, Kp, Vp, qf, o, m, lsum, Plds[wave]);

    // ---- normalize + store ctx [B][S][NHEAD][DK] bf16 ----
    #pragma unroll
    for (int dkc = 0; dkc < 4; ++dkc) {
        #pragma unroll
        for (int v = 0; v < 4; ++v) {
            const int qg = qb + l4*4 + v;
            const int dk = dkc*16 + l15;
            const float val = o[dkc][v] / lsum[v];
            Ctx[(((size_t)b * S_LEN + qg) * NHEAD + h) * HDIM + dk] = f32_bf16(val);
        }
    }
}

// ---------------- launch ----------------
// ws layout (ushorts), Ctx aliases xb (dead after QKV GEMMs). Total ~23 MiB.
extern "C" void kernel_launch(void* const* d_in, const int* in_sizes, int n_in,
                              void* d_out, int out_size, void* d_ws, size_t ws_size,
                              hipStream_t stream) {
    const float* x  = (const float*)d_in[0];
    const float* wq = (const float*)d_in[1];
    const float* wk = (const float*)d_in[2];
    const float* wv = (const float*)d_in[3];
    const float* wo = (const float*)d_in[4];
    float* out = (float*)d_out;

    const int M = NBATCH * S_LEN;          // 4096
    const int nX  = M * DMODEL;            // 4194304
    const int nWq = DMODEL * NHEAD * HDIM; // 1048576
    const int nWk = DMODEL * NKV * HDIM;   // 262144
    const int nWo = DMODEL * DMODEL;       // 1048576
    const int nQ  = NBATCH * NHEAD * S_LEN * HDIM;  // 4194304
    const int nKV = NBATCH * NKV * S_LEN * HDIM;    // 1048576

    unsigned short* xb  = (unsigned short*)d_ws;
    unsigned short* wqb = xb  + nX;
    unsigned short* wkb = wqb + nWq;
    unsigned short* wvb = wkb + nWk;
    unsigned short* wob = wvb + nWk;
    unsigned short* Qb  = wob + nWo;
    unsigned short* Kb  = Qb  + nQ;
    unsigned short* Vbuf= Kb  + nKV;
    unsigned short* Ctx = xb;              // alias: xb dead after QKV GEMMs

    cvt_bf16_k<<<nX  / 1024, 256, 0, stream>>>(x,  xb,  nX  / 4);
    cvt_bf16_k<<<nWq / 1024, 256, 0, stream>>>(wq, wqb, nWq / 4);
    cvt_bf16_k<<<nWk / 1024, 256, 0, stream>>>(wk, wkb, nWk / 4);
    cvt_bf16_k<<<nWk / 1024, 256, 0, stream>>>(wv, wvb, nWk / 4);
    cvt_bf16_k<<<nWo / 1024, 256, 0, stream>>>(wo, wob, nWo / 4);

    // Q: rope + QSCALE (exp2-domain softmax). K: rope only. V: transposed store.
    gemm_k<1><<<dim3((NHEAD*HDIM)/64, M/64), 256, 0, stream>>>(xb, wqb, Qb,   NHEAD*HDIM, DMODEL, NHEAD, QSCALE);
    gemm_k<1><<<dim3((NKV*HDIM)/64,  M/64), 256, 0, stream>>>(xb, wkb, Kb,   NKV*HDIM,  DMODEL, NKV,  1.0f);
    gemm_k<3><<<dim3((NKV*HDIM)/64,  M/64), 256, 0, stream>>>(xb, wvb, Vbuf, NKV*HDIM,  DMODEL, NKV,  1.0f);

    attn_k<<<dim3(S_LEN/64, NHEAD, NBATCH), 256, 0, stream>>>(Qb, Kb, Vbuf, Ctx);

    gemm_k<0><<<dim3(DMODEL/64, M/64), 256, 0, stream>>>(Ctx, wob, out, DMODEL, DMODEL, 0, 1.0f);
}

// Round 4
// 387.055 us; speedup vs baseline: 1.0019x; 1.0019x over previous
//
#include <hip/hip_runtime.h>
#include <hip/hip_bf16.h>

#define S_LEN 2048
#define NBATCH 2
#define DMODEL 1024
#define NHEAD 16
#define NKV 4
#define HDIM 64

typedef __attribute__((ext_vector_type(4))) float f32x4;
typedef __attribute__((ext_vector_type(8))) short s16x8;

// 0.125 (1/sqrt(dk)) * log2(e): Q pre-scale so softmax runs in exp2 domain
#define QSCALE 0.18033688011112042f

__device__ __forceinline__ unsigned short f32_bf16(float f) {
    unsigned int u = __float_as_uint(f);
    u += 0x7FFFu + ((u >> 16) & 1u);
    return (unsigned short)(u >> 16);
}

// ---------------- f32 -> bf16 convert ----------------
__global__ __launch_bounds__(256) void cvt_bf16_k(const float* __restrict__ in,
                                                  unsigned short* __restrict__ out, int n4) {
    int i = blockIdx.x * 256 + threadIdx.x;
    if (i < n4) {
        const float4 v = reinterpret_cast<const float4*>(in)[i];
        ushort4 r;
        r.x = f32_bf16(v.x); r.y = f32_bf16(v.y);
        r.z = f32_bf16(v.z); r.w = f32_bf16(v.w);
        reinterpret_cast<ushort4*>(out)[i] = r;
    }
}

// ---------------- GEMM: C[M][N] = A[M][K] @ W[K][N], bf16 in, f32 acc ----------------
// EPI 0: f32 row-major out.
// EPI 1: rope + *oscale + bf16 head-layout [B][nheads][S][DK].
// EPI 3: bf16 TRANSPOSED head-layout [B][nheads][DK][S]  (for V)
template<int EPI>
__global__ __launch_bounds__(256) void gemm_k(
    const unsigned short* __restrict__ A,
    const unsigned short* __restrict__ W,
    void* __restrict__ Out, int N, int K, int nheads, float oscale)
{
    __shared__ unsigned short As[64][72];   // [m][k], +8 pad
    __shared__ unsigned short Bs[64][72];   // [n][k] (transposed), +8 pad

    const int tid  = threadIdx.x;
    const int lane = tid & 63;
    const int l15  = lane & 15;
    const int l4   = lane >> 4;
    const int wave = tid >> 6;
    const int wr   = (wave >> 1) * 32;
    const int wc   = (wave & 1) * 32;
    const int bm   = blockIdx.y * 64;
    const int bn   = blockIdx.x * 64;

    f32x4 acc[2][2] = {};

    for (int k0 = 0; k0 < K; k0 += 64) {
        #pragma unroll
        for (int cc = 0; cc < 2; ++cc) {
            const int c   = tid + cc * 256;      // 512 chunks of 8 elems
            const int row = c >> 3;
            const int col = (c & 7) * 8;
            *reinterpret_cast<s16x8*>(&As[row][col]) =
                *reinterpret_cast<const s16x8*>(A + (size_t)(bm + row) * K + k0 + col);
            const s16x8 wv =
                *reinterpret_cast<const s16x8*>(W + (size_t)(k0 + row) * N + bn + col);
            #pragma unroll
            for (int i = 0; i < 8; ++i) Bs[col + i][row] = (short)wv[i];
        }
        __syncthreads();
        #pragma unroll
        for (int ks = 0; ks < 2; ++ks) {
            s16x8 af[2], bfv[2];
            #pragma unroll
            for (int i = 0; i < 2; ++i)
                af[i] = *reinterpret_cast<const s16x8*>(&As[wr + i*16 + l15][ks*32 + l4*8]);
            #pragma unroll
            for (int j = 0; j < 2; ++j)
                bfv[j] = *reinterpret_cast<const s16x8*>(&Bs[wc + j*16 + l15][ks*32 + l4*8]);
            #pragma unroll
            for (int i = 0; i < 2; ++i)
                #pragma unroll
                for (int j = 0; j < 2; ++j)
                    acc[i][j] = __builtin_amdgcn_mfma_f32_16x16x32_bf16(
                        af[i], bfv[j], acc[i][j], 0, 0, 0);
        }
        __syncthreads();
    }

    #pragma unroll
    for (int i = 0; i < 2; ++i) {
        #pragma unroll
        for (int j = 0; j < 2; ++j) {
            #pragma unroll
            for (int v = 0; v < 4; ++v) {
                const int gr = bm + wr + i*16 + l4*4 + v;
                const int gc = bn + wc + j*16 + l15;
                float val = acc[i][j][v];
                if (EPI == 0) {
                    reinterpret_cast<float*>(Out)[(size_t)gr * N + gc] = val;
                } else {
                    if (EPI == 1) {
                        const float partner = __shfl_xor(val, 1, 64);
                        const int   jp = (gc & 63) >> 1;      // pair index 0..31
                        const int   hh = gc >> 6;             // head index
                        // inv_freq = 10000^(-2*jp/64)
                        const float inv = __expf((float)jp * (-2.0f / 64.0f) * 9.210340371976184f);
                        const float ang = (float)hh * inv;
                        float sn, cs;
                        __sincosf(ang, &sn, &cs);
                        val = ((gc & 1) == 0) ? (val * cs - partner * sn)
                                              : (partner * sn + val * cs);
                        val *= oscale;
                    }
                    const int b  = gr >> 11;       // / S_LEN
                    const int sr = gr & (S_LEN - 1);
                    const int hh = gc >> 6;
                    const int dk = gc & 63;
                    if (EPI == 3) {
                        reinterpret_cast<unsigned short*>(Out)[
                            (((size_t)b * nheads + hh) * HDIM + dk) * S_LEN + sr] = f32_bf16(val);
                    } else {
                        reinterpret_cast<unsigned short*>(Out)[
                            (((size_t)b * nheads + hh) * S_LEN + sr) * HDIM + dk] = f32_bf16(val);
                    }
                }
            }
        }
    }
}

// ---------------- flash attention (causal, GQA), swapped-operand form ----------------
// Q: [B][NHEAD][S][DK] bf16 (rope+QSCALE applied), K: [B][NKV][S][DK],
// Vt: [B][NKV][DK][S] (transposed), Ctx out: [B][S][NHEAD][DK] bf16.
// QK^T computed as mfma(K,Q) -> D = S^T[kv][q]: lane owns ONE q (=lane&15),
// softmax is 15 in-reg ops + 2 shfl_xor. PV computed as O^T = V^T @ P.
template<bool MASK>
__device__ __forceinline__ void attn_step64(
    int kv0, int qb, int l15, int l4,
    const unsigned short* __restrict__ Kp,
    const unsigned short* __restrict__ Vp,
    const s16x8 qf[2], f32x4 o[4], float& m, float& lsum,
    unsigned short (*Plds)[80])
{
    // ---- hoisted loads: K (QK A-operand) and V^T (PV A-operand) ----
    s16x8 kf[4][2], vf[4][2];
    #pragma unroll
    for (int c = 0; c < 4; ++c)
        #pragma unroll
        for (int ks = 0; ks < 2; ++ks)
            kf[c][ks] = *reinterpret_cast<const s16x8*>(
                Kp + (size_t)(kv0 + c*16 + l15) * HDIM + ks*32 + l4*8);
    #pragma unroll
    for (int dkc = 0; dkc < 4; ++dkc)
        #pragma unroll
        for (int ks = 0; ks < 2; ++ks)
            vf[dkc][ks] = *reinterpret_cast<const s16x8*>(
                Vp + (size_t)(dkc*16 + l15) * S_LEN + kv0 + ks*32 + l4*8);

    // ---- S^T[kv][q]: lane holds kv = c*16 + l4*4 + v for q = l15 ----
    f32x4 s[4] = {};
    #pragma unroll
    for (int c = 0; c < 4; ++c)
        #pragma unroll
        for (int ks = 0; ks < 2; ++ks)
            s[c] = __builtin_amdgcn_mfma_f32_16x16x32_bf16(kf[c][ks], qf[ks], s[c], 0, 0, 0);

    const int qg = qb + l15;
    if (MASK) {
        #pragma unroll
        for (int c = 0; c < 4; ++c)
            #pragma unroll
            for (int v = 0; v < 4; ++v) {
                const int kvg = kv0 + c*16 + l4*4 + v;
                s[c][v] = (kvg <= qg) ? s[c][v] : -1e30f;
            }
    }

    // ---- online softmax, lane-local + 2-shuffle cross-l4 reduce ----
    float mx = -1e30f;
    #pragma unroll
    for (int c = 0; c < 4; ++c)
        #pragma unroll
        for (int v = 0; v < 4; ++v) mx = fmaxf(mx, s[c][v]);
    mx = fmaxf(mx, __shfl_xor(mx, 16, 64));
    mx = fmaxf(mx, __shfl_xor(mx, 32, 64));
    const float mnew  = fmaxf(m, mx);
    const float scale = __builtin_amdgcn_exp2f(m - mnew);
    float psum = 0.0f;
    #pragma unroll
    for (int c = 0; c < 4; ++c)
        #pragma unroll
        for (int v = 0; v < 4; ++v) {
            const float p = __builtin_amdgcn_exp2f(s[c][v] - mnew);
            s[c][v] = p;
            psum += p;
        }
    psum += __shfl_xor(psum, 16, 64);
    psum += __shfl_xor(psum, 32, 64);
    lsum = lsum * scale + psum;
    m = mnew;
    #pragma unroll
    for (int dkc = 0; dkc < 4; ++dkc) o[dkc] *= scale;

    // ---- P^T -> LDS [q][kv] (packed bf16 pairs, 4x ds_write_b64) ----
    #pragma unroll
    for (int c = 0; c < 4; ++c) {
        uint2 w;
        w.x = (unsigned int)f32_bf16(s[c][0]) | ((unsigned int)f32_bf16(s[c][1]) << 16);
        w.y = (unsigned int)f32_bf16(s[c][2]) | ((unsigned int)f32_bf16(s[c][3]) << 16);
        *reinterpret_cast<uint2*>(&Plds[l15][c*16 + l4*4]) = w;
    }
    // ---- B-frag read: P[kv][q], contiguous in kv for q = l15 ----
    s16x8 pb[2];
    #pragma unroll
    for (int ks = 0; ks < 2; ++ks)
        pb[ks] = *reinterpret_cast<const s16x8*>(&Plds[l15][ks*32 + l4*8]);

    // ---- O^T[dk][q] += V^T[dk][kv] @ P[kv][q] ----
    #pragma unroll
    for (int dkc = 0; dkc < 4; ++dkc)
        #pragma unroll
        for (int ks = 0; ks < 2; ++ks)
            o[dkc] = __builtin_amdgcn_mfma_f32_16x16x32_bf16(vf[dkc][ks], pb[ks], o[dkc], 0, 0, 0);
}

__global__ __launch_bounds__(256) void attn_k(
    const unsigned short* __restrict__ Q,
    const unsigned short* __restrict__ Kb,
    const unsigned short* __restrict__ Vt,
    unsigned short* __restrict__ Ctx)
{
    __shared__ unsigned short Plds[4][16][80];  // per-wave P tile [q16][kv64], row 80 shorts

    const int tid  = threadIdx.x;
    const int lane = tid & 63;
    const int l15  = lane & 15;
    const int l4   = lane >> 4;
    const int wave = tid >> 6;

    // reversed order: biggest causal blocks launch first (LPT)
    const int qb0 = (gridDim.x - 1 - blockIdx.x) * 64;
    const int h   = blockIdx.y;
    const int b   = blockIdx.z;
    const int g   = h >> 2;   // kv head

    const unsigned short* Qp = Q  + ((size_t)b * NHEAD + h) * S_LEN * HDIM;
    const unsigned short* Kp = Kb + ((size_t)b * NKV  + g) * S_LEN * HDIM;
    const unsigned short* Vp = Vt + ((size_t)b * NKV  + g) * HDIM * S_LEN;

    const int qb = qb0 + wave * 16;   // this wave's 16 q-rows

    // Q fragments (B-operand of swapped QK^T): lane reads Q[qb+l15][k-slice]
    s16x8 qf[2];
    #pragma unroll
    for (int ks = 0; ks < 2; ++ks)
        qf[ks] = *reinterpret_cast<const s16x8*>(Qp + (size_t)(qb + l15) * HDIM + ks*32 + l4*8);

    f32x4 o[4] = {};
    float m = -1e30f, lsum = 0.0f;

    const int kvend = qb + 16;   // causal bound
    const int full_end = (qb >= 63) ? ((((qb - 63) >> 6) << 6) + 64) : 0;

    int kv0 = 0;
    for (; kv0 < full_end; kv0 += 64)
        attn_step64<false>(kv0, qb, l15, l4, Kp, Vp, qf, o, m, lsum, Plds[wave]);
    for (; kv0 < kvend; kv0 += 64)
        attn_step64<true >(kv0, qb, l15, l4, Kp, Vp, qf, o, m, lsum, Plds[wave]);

    // ---- normalize + store ctx [B][S][NHEAD][DK] bf16 (q = l15) ----
    const float inv = 1.0f / lsum;
    unsigned short* cp = Ctx + (((size_t)b * S_LEN + qb + l15) * NHEAD + h) * HDIM;
    #pragma unroll
    for (int dkc = 0; dkc < 4; ++dkc) {
        ushort4 r;
        r.x = f32_bf16(o[dkc][0] * inv);
        r.y = f32_bf16(o[dkc][1] * inv);
        r.z = f32_bf16(o[dkc][2] * inv);
        r.w = f32_bf16(o[dkc][3] * inv);
        *reinterpret_cast<ushort4*>(cp + dkc*16 + l4*4) = r;
    }
}

// ---------------- launch ----------------
// ws layout (ushorts), Ctx aliases xb (dead after QKV GEMMs). Total ~23 MiB.
extern "C" void kernel_launch(void* const* d_in, const int* in_sizes, int n_in,
                              void* d_out, int out_size, void* d_ws, size_t ws_size,
                              hipStream_t stream) {
    const float* x  = (const float*)d_in[0];
    const float* wq = (const float*)d_in[1];
    const float* wk = (const float*)d_in[2];
    const float* wv = (const float*)d_in[3];
    const float* wo = (const float*)d_in[4];
    float* out = (float*)d_out;

    const int M = NBATCH * S_LEN;          // 4096
    const int nX  = M * DMODEL;            // 4194304
    const int nWq = DMODEL * NHEAD * HDIM; // 1048576
    const int nWk = DMODEL * NKV * HDIM;   // 262144
    const int nWo = DMODEL * DMODEL;       // 1048576
    const int nQ  = NBATCH * NHEAD * S_LEN * HDIM;  // 4194304
    const int nKV = NBATCH * NKV * S_LEN * HDIM;    // 1048576

    unsigned short* xb  = (unsigned short*)d_ws;
    unsigned short* wqb = xb  + nX;
    unsigned short* wkb = wqb + nWq;
    unsigned short* wvb = wkb + nWk;
    unsigned short* wob = wvb + nWk;
    unsigned short* Qb  = wob + nWo;
    unsigned short* Kb  = Qb  + nQ;
    unsigned short* Vbuf= Kb  + nKV;
    unsigned short* Ctx = xb;              // alias: xb dead after QKV GEMMs

    cvt_bf16_k<<<nX  / 1024, 256, 0, stream>>>(x,  xb,  nX  / 4);
    cvt_bf16_k<<<nWq / 1024, 256, 0, stream>>>(wq, wqb, nWq / 4);
    cvt_bf16_k<<<nWk / 1024, 256, 0, stream>>>(wk, wkb, nWk / 4);
    cvt_bf16_k<<<nWk / 1024, 256, 0, stream>>>(wv, wvb, nWk / 4);
    cvt_bf16_k<<<nWo / 1024, 256, 0, stream>>>(wo, wob, nWo / 4);

    // Q: rope + QSCALE (exp2-domain softmax). K: rope only. V: transposed store.
    gemm_k<1><<<dim3((NHEAD*HDIM)/64, M/64), 256, 0, stream>>>(xb, wqb, Qb,   NHEAD*HDIM, DMODEL, NHEAD, QSCALE);
    gemm_k<1><<<dim3((NKV*HDIM)/64,  M/64), 256, 0, stream>>>(xb, wkb, Kb,   NKV*HDIM,  DMODEL, NKV,  1.0f);
    gemm_k<3><<<dim3((NKV*HDIM)/64,  M/64), 256, 0, stream>>>(xb, wvb, Vbuf, NKV*HDIM,  DMODEL, NKV,  1.0f);

    attn_k<<<dim3(S_LEN/64, NHEAD, NBATCH), 256, 0, stream>>>(Qb, Kb, Vbuf, Ctx);

    gemm_k<0><<<dim3(DMODEL/64, M/64), 256, 0, stream>>>(Ctx, wob, out, DMODEL, DMODEL, 0, 1.0f);
}